// Round 4
// baseline (264.434 us; speedup 1.0000x reference)
//
#include <hip/hip_runtime.h>

#define BB 4
#define SS 2048
#define DD 1024
#define HH 16
#define DHH 64
#define MM (BB*SS)          // 8192

typedef __bf16 bf16x8 __attribute__((ext_vector_type(8)));
typedef __bf16 bf16x4 __attribute__((ext_vector_type(4)));
typedef float  f32x4  __attribute__((ext_vector_type(4)));
typedef float  f32x16 __attribute__((ext_vector_type(16)));
typedef unsigned int u32;
typedef unsigned int u32x4 __attribute__((ext_vector_type(4)));

__device__ __forceinline__ unsigned short f2bf(float x) {
    unsigned int u = __float_as_uint(x);
    u += 0x7FFFu + ((u >> 16) & 1u);          // RNE
    return (unsigned short)(u >> 16);
}

// Async global->LDS, 16B/lane. LDS dst is wave-uniform base + lane*16.
__device__ __forceinline__ void glds16(const __bf16* g, __bf16* l) {
    __builtin_amdgcn_global_load_lds(
        (const __attribute__((address_space(1))) void*)g,
        (__attribute__((address_space(3))) void*)l, 16, 0, 0);
}

// ---------------------------------------------------------------------------
// fp32 -> bf16, all three inputs in one launch.
// ---------------------------------------------------------------------------
__global__ __launch_bounds__(256) void cvt_all(
    const float4* __restrict__ x,  const float4* __restrict__ wq,
    const float4* __restrict__ wo,
    ushort4* __restrict__ xb, ushort4* __restrict__ wqb, ushort4* __restrict__ wob)
{
    int i = blockIdx.x * 256 + threadIdx.x;
    const float4* src; ushort4* dst; int j;
    if (i < 2097152)      { src = x;  dst = xb;  j = i; }
    else if (i < 2883584) { src = wq; dst = wqb; j = i - 2097152; }
    else                  { src = wo; dst = wob; j = i - 2883584; }
    float4 v = src[j];
    ushort4 o;
    o.x = f2bf(v.x); o.y = f2bf(v.y); o.z = f2bf(v.z); o.w = f2bf(v.w);
    dst[j] = o;
}

// ---------------------------------------------------------------------------
// MFMA GEMM (B^T): C[m,n] = sum_k A[m,k] * W[n,k]. 128x128 tile, BK=64,
// 4 waves (2x2 of 64x64), 16x16x32 frags. Staging via global_load_lds
// width=16 into unpadded [128][64] tiles, rotate-by-row granule swizzle
// (2-way bank aliasing per 16-lane phase = free).
// ---------------------------------------------------------------------------
__global__ __launch_bounds__(256) void qkv_gemm(
    const __bf16* __restrict__ A,             // [8192,1024] x
    const __bf16* __restrict__ W,             // [3072,1024] W_qkv
    const float* __restrict__ bias,           // [3072]
    __bf16* __restrict__ Qp,                  // [64][2048][64], pre-scaled
    __bf16* __restrict__ Kp,                  // [64][2048][64]
    __bf16* __restrict__ Vp)                  // [64][64][2048] transposed
{
    __shared__ __bf16 smem[16896];            // As(8192) | Bs(8192); CT[128][132]
#define CT(r,c) smem[(r)*132 + (c)]
    __bf16* As = smem;
    __bf16* Bs = smem + 8192;
    const int tid  = threadIdx.x;
    const int m0   = blockIdx.x * 128;
    const int n0   = blockIdx.y * 128;
    const int lane = tid & 63;
    const int wid  = tid >> 6;
    const int fr   = lane & 15;
    const int quad = lane >> 4;
    const int wm   = (wid >> 1) * 64;
    const int wn   = (wid & 1) * 64;

    const int srow = lane >> 3;               // 0..7 within a wave-chunk
    const int sg   = ((lane & 7) - srow) & 7; // swizzled granule to fetch

    f32x4 acc[4][4] = {};

    for (int k0 = 0; k0 < DD; k0 += 64) {
        __syncthreads();
        #pragma unroll
        for (int p = 0; p < 4; ++p) {
            int cidx = p * 4 + wid;           // 0..15 -> rows 8*cidx..+7
            int r = cidx * 8 + srow;
            glds16(A + (size_t)(m0 + r) * DD + k0 + sg * 8, As + cidx * 512);
            glds16(W + (size_t)(n0 + r) * DD + k0 + sg * 8, Bs + cidx * 512);
        }
        __syncthreads();

        bf16x8 af[2][4], bw[2][4];
        #pragma unroll
        for (int kc = 0; kc < 2; ++kc)
            #pragma unroll
            for (int t = 0; t < 4; ++t) {
                int col = ((kc * 4 + quad + fr) & 7) * 8;
                af[kc][t] = *(const bf16x8*)&As[(wm + t*16 + fr) * 64 + col];
                bw[kc][t] = *(const bf16x8*)&Bs[(wn + t*16 + fr) * 64 + col];
            }
        #pragma unroll
        for (int kc = 0; kc < 2; ++kc)
            #pragma unroll
            for (int mt = 0; mt < 4; ++mt)
                #pragma unroll
                for (int nt = 0; nt < 4; ++nt)
                    acc[mt][nt] = __builtin_amdgcn_mfma_f32_16x16x32_bf16(
                        af[kc][mt], bw[kc][nt], acc[mt][nt], 0, 0, 0);
    }

    __syncthreads();                          // staging reads done; reuse smem
    const int t3 = n0 >> 10;                  // 0=q, 1=k, 2=v (uniform/block)
    const int b  = m0 >> 11;
    const int s0 = m0 & (SS - 1);

    float bn[4];
    #pragma unroll
    for (int nt = 0; nt < 4; ++nt) bn[nt] = bias[n0 + wn + nt*16 + fr];

    if (t3 == 2) {
        // V: store tile TRANSPOSED in LDS: CT[n-local][m-local], packed b64.
        #pragma unroll
        for (int nt = 0; nt < 4; ++nt)
            #pragma unroll
            for (int mt = 0; mt < 4; ++mt) {
                f32x4 t;
                #pragma unroll
                for (int i = 0; i < 4; ++i) t[i] = acc[mt][nt][i] + bn[nt];
                *(bf16x4*)&CT(wn + nt*16 + fr, wm + mt*16 + quad*4) =
                    __builtin_convertvector(t, bf16x4);
            }
        __syncthreads();
        const int pn0 = n0 - 2048;
        #pragma unroll
        for (int p = 0; p < 8; ++p) {
            int g = tid + p * 256;
            int r = g >> 4;                   // n-local 0..127
            int c = (g & 15) << 3;            // m-local 0..120
            int pn = pn0 + r, h = pn >> 6, dh = pn & 63;
            *(uint4*)&Vp[((size_t)((b*HH + h)*DHH + dh))*SS + s0 + c] = *(uint4*)&CT(r, c);
        }
    } else {
        __bf16* dst = (t3 == 0) ? Qp : Kp;
        // Q pre-scale folds 1/sqrt(64) AND log2(e) (softmax uses exp2).
        const float qscale = (t3 == 0) ? 0.125f * 1.44269504088896340736f : 1.0f;
        #pragma unroll
        for (int nt = 0; nt < 4; ++nt)
            #pragma unroll
            for (int mt = 0; mt < 4; ++mt)
                #pragma unroll
                for (int i = 0; i < 4; ++i)
                    CT(wm + mt*16 + quad*4 + i, wn + nt*16 + fr) =
                        (__bf16)((acc[mt][nt][i] + bn[nt]) * qscale);
        __syncthreads();
        const int pn0 = (t3 == 0) ? n0 : n0 - 1024;
        #pragma unroll
        for (int p = 0; p < 8; ++p) {
            int g = tid + p * 256;
            int r = g >> 4;                   // m-local (s) 0..127
            int c = (g & 15) << 3;            // n-local 0..120
            int pn = pn0 + c, h = pn >> 6, dh = pn & 63;
            *(uint4*)&dst[((size_t)((b*HH + h))*SS + s0 + r)*DHH + dh] = *(uint4*)&CT(r, c);
        }
    }
#undef CT
}

__global__ __launch_bounds__(256) void out_gemm(
    const __bf16* __restrict__ A,             // [8192,1024] O bf16
    const __bf16* __restrict__ W,             // [1024,1024] W_out bf16
    const float* __restrict__ bias,           // [1024]
    float* __restrict__ out)                  // [8192,1024] fp32
{
    __shared__ __bf16 smem[16384];            // As(8192) | Bs(8192)
    __bf16* As = smem;
    __bf16* Bs = smem + 8192;
    const int tid  = threadIdx.x;
    const int m0   = blockIdx.x * 128;
    const int n0   = blockIdx.y * 128;
    const int lane = tid & 63;
    const int wid  = tid >> 6;
    const int fr   = lane & 15;
    const int quad = lane >> 4;
    const int wm   = (wid >> 1) * 64;
    const int wn   = (wid & 1) * 64;

    const int srow = lane >> 3;
    const int sg   = ((lane & 7) - srow) & 7;

    f32x4 acc[4][4] = {};

    for (int k0 = 0; k0 < DD; k0 += 64) {
        __syncthreads();
        #pragma unroll
        for (int p = 0; p < 4; ++p) {
            int cidx = p * 4 + wid;
            int r = cidx * 8 + srow;
            glds16(A + (size_t)(m0 + r) * DD + k0 + sg * 8, As + cidx * 512);
            glds16(W + (size_t)(n0 + r) * DD + k0 + sg * 8, Bs + cidx * 512);
        }
        __syncthreads();

        bf16x8 af[2][4], bw[2][4];
        #pragma unroll
        for (int kc = 0; kc < 2; ++kc)
            #pragma unroll
            for (int t = 0; t < 4; ++t) {
                int col = ((kc * 4 + quad + fr) & 7) * 8;
                af[kc][t] = *(const bf16x8*)&As[(wm + t*16 + fr) * 64 + col];
                bw[kc][t] = *(const bf16x8*)&Bs[(wn + t*16 + fr) * 64 + col];
            }
        #pragma unroll
        for (int kc = 0; kc < 2; ++kc)
            #pragma unroll
            for (int mt = 0; mt < 4; ++mt)
                #pragma unroll
                for (int nt = 0; nt < 4; ++nt)
                    acc[mt][nt] = __builtin_amdgcn_mfma_f32_16x16x32_bf16(
                        af[kc][mt], bw[kc][nt], acc[mt][nt], 0, 0, 0);
    }

    #pragma unroll
    for (int nt = 0; nt < 4; ++nt) {
        int n  = n0 + wn + nt*16 + fr;
        float bnv = bias[n];
        #pragma unroll
        for (int mt = 0; mt < 4; ++mt) {
            #pragma unroll
            for (int i = 0; i < 4; ++i) {
                int m = m0 + wm + mt*16 + quad*4 + i;
                out[(size_t)m * DD + n] = acc[mt][nt][i] + bnv;
            }
        }
    }
}

// ---------------------------------------------------------------------------
// MFMA flash attention v10: v9 (32x32x16 + in-register T12 P relayout) with
// DOUBLED TLP. R2 post-mortem: no pipe >40% -> latency/dependency-bound at
// 2 waves/SIMD. Grid is fixed at 512 blocks, so occupancy must come from
// block shape: 512 threads / 8 waves, 32 q-rows per wave -> 16 waves/CU =
// 4 waves/SIMD at the same 2 blocks/CU. LDS shrunk to make this free:
// Ps (36K) is epilogue-only since v9 -> alias it over the Ks/VT double
// buffers (all staging reads complete at the final round's barrier).
// LDS = union(32K staging, 36K Ps) + Ls 1K = 37.9K -> 2 blocks x 512thr/CU.
// ---------------------------------------------------------------------------
__global__ __launch_bounds__(512, 4) void attn_mfma(
    const __bf16* __restrict__ Qp,            // [bh][s][dh], pre-scaled
    const __bf16* __restrict__ Kp,            // [bh][s][dh]
    const __bf16* __restrict__ Vp,            // [bh][dh][s]  (transposed)
    __bf16* __restrict__ Op)                  // [8192][1024] (b,s,h*dh)
{
    // [0,16384)      Ks[2][4096]  (rot-8 swizzled, double-buffered)
    // [16384,32768)  VT[2][4096]  (rot-8 swizzled, double-buffered)
    // [0,36864)      Ps[256][72]  (EPILOGUE ONLY - aliases staging)
    // [36864,37888)  Ls[256]      (denominators, non-aliased)
    __shared__ __align__(16) char smem[37888];
    __bf16* const KsB = (__bf16*)smem;
    __bf16* const VTB = (__bf16*)(smem + 16384);
    float*  const Ls  = (float*)(smem + 36864);
#define PS(r,c) (((__bf16*)smem)[(r)*72 + (c)])

    const int tid  = threadIdx.x;
    const int q0   = blockIdx.x * 256;
    const int bh   = blockIdx.y;
    const size_t base = (size_t)bh * SS * DHH;
    const int lane = tid & 63;
    const int wid  = tid >> 6;                // 0..7
    const int c32  = lane & 31;               // row/col index in 32-wide frags
    const int hi   = lane >> 5;               // half-wave select
    const int wrow = wid * 32;                // this wave's q-rows in tile

    const int srow = lane >> 3;
    const int sg   = ((lane & 7) - srow) & 7;

    // 8 waves each stage 8 rows of K and 8 rows of V (1 glds16 each).
#define STAGE_KV(buf, kt_)                                                        \
    {                                                                             \
        int r = wid * 8 + srow;                                                   \
        glds16(Kp + base + (size_t)((kt_) + r) * DHH + sg * 8,                    \
               KsB + (buf) * 4096 + wid * 512);                                   \
        glds16(Vp + base + (size_t)r * SS + (kt_) + sg * 8,                       \
               VTB + (buf) * 4096 + wid * 512);                                   \
    }

    // Q B-frags from global: B[k=d][col=q]; lane holds Q[q=c32][ks*16+hi*8+j].
    bf16x8 bq[4];
    #pragma unroll
    for (int ks = 0; ks < 4; ++ks)
        bq[ks] = *(const bf16x8*)
            (Qp + base + (size_t)(q0 + wrow + c32) * DHH + ks*16 + hi*8);

    f32x16 o[2] = {};                         // o[dt]
    float lp = 0.0f;

    STAGE_KV(0, 0)
    __syncthreads();                          // prologue tile landed

    int cur = 0;
    for (int kt = 0; kt < SS; kt += 64) {
        if (kt + 64 < SS) STAGE_KV(cur ^ 1, kt + 64)   // async prefetch
        const __bf16* Kc = KsB + cur * 4096;
        const __bf16* Vc = VTB + cur * 4096;

        u32 pw[2][8];                         // packed P A-frags [kt2][dword]

        // S^T = K Q^T, 32x32x16: D[key = (reg&3)+8*(reg>>2)+4*hi][q = c32].
        #pragma unroll
        for (int kt2 = 0; kt2 < 2; ++kt2) {
            bf16x8 bk[4];
            #pragma unroll
            for (int ks = 0; ks < 4; ++ks)
                bk[ks] = *(const bf16x8*)
                    &Kc[(kt2*32 + c32) * 64 + ((ks*2 + hi + c32) & 7) * 8];
            f32x16 s = {};
            __builtin_amdgcn_s_setprio(1);
            #pragma unroll
            for (int ks = 0; ks < 4; ++ks)
                s = __builtin_amdgcn_mfma_f32_32x32x16_bf16(
                    bk[ks], bq[ks], s, 0, 0, 0);
            __builtin_amdgcn_s_setprio(0);
            #pragma unroll
            for (int e = 0; e < 16; ++e) s[e] = __builtin_amdgcn_exp2f(s[e]);
            lp += ((s[0]+s[1])+(s[2]+s[3])) + ((s[4]+s[5])+(s[6]+s[7]))
                + ((s[8]+s[9])+(s[10]+s[11])) + ((s[12]+s[13])+(s[14]+s[15]));
            // T12 relayout: 4 cvt_pk + 2 permlane32_swap per 16-key step.
            #pragma unroll
            for (int kk = 0; kk < 2; ++kk) {
                u32 wa, wb, wc, wd;
                asm("v_cvt_pk_bf16_f32 %0, %1, %2" : "=v"(wa) : "v"(s[kk*8+0]), "v"(s[kk*8+1]));
                asm("v_cvt_pk_bf16_f32 %0, %1, %2" : "=v"(wb) : "v"(s[kk*8+4]), "v"(s[kk*8+5]));
                asm("v_cvt_pk_bf16_f32 %0, %1, %2" : "=v"(wc) : "v"(s[kk*8+2]), "v"(s[kk*8+3]));
                asm("v_cvt_pk_bf16_f32 %0, %1, %2" : "=v"(wd) : "v"(s[kk*8+6]), "v"(s[kk*8+7]));
                asm("v_permlane32_swap_b32 %0, %1" : "+v"(wa), "+v"(wb));
                asm("v_permlane32_swap_b32 %0, %1" : "+v"(wc), "+v"(wd));
                pw[kt2][kk*4+0] = wa;
                pw[kt2][kk*4+1] = wc;
                pw[kt2][kk*4+2] = wb;
                pw[kt2][kk*4+3] = wd;
            }
        }

        // O += P V, 32x32x16: A = P[q][k] (in-register), B = V[k][d] from VT.
        #pragma unroll
        for (int ks = 0; ks < 4; ++ks) {
            const int kt2 = ks >> 1, kk = ks & 1;
            bf16x8 bv[2];
            #pragma unroll
            for (int dt = 0; dt < 2; ++dt)
                bv[dt] = *(const bf16x8*)
                    &Vc[(dt*32 + c32) * 64 + ((ks*2 + hi + c32) & 7) * 8];
            u32x4 t = { pw[kt2][kk*4+0], pw[kt2][kk*4+1],
                        pw[kt2][kk*4+2], pw[kt2][kk*4+3] };
            bf16x8 pa = __builtin_bit_cast(bf16x8, t);
            __builtin_amdgcn_s_setprio(1);
            #pragma unroll
            for (int dt = 0; dt < 2; ++dt)
                o[dt] = __builtin_amdgcn_mfma_f32_32x32x16_bf16(
                    pa, bv[dt], o[dt], 0, 0, 0);
            __builtin_amdgcn_s_setprio(0);
        }

        __syncthreads();                      // drains prefetch + syncs bufs
        cur ^= 1;
    }
#undef STAGE_KV

    // Denominators: lane (q=c32, hi) holds 32 of 64 keys/round; partner
    // half-wave has the rest -> single xor-32 reduce. Same-wave LDS use.
    {
        float v = lp + __shfl_xor(lp, 32);
        Ls[wrow + c32] = v;                   // both hi write same value
    }

    // Normalize O (D[row=q][col=d], row = (reg&3)+8*(reg>>2)+4*hi) and stage
    // into Ps (which aliases the now-dead staging buffers).
    #pragma unroll
    for (int r = 0; r < 16; ++r) {
        int row = wrow + (r & 3) + 8*(r >> 2) + 4*hi;
        float inv = 1.0f / Ls[row];
        #pragma unroll
        for (int dt = 0; dt < 2; ++dt)
            PS(row, dt*32 + c32) = (__bf16)(o[dt][r] * inv);
    }
    __syncthreads();

    const int b = bh >> 4, h = bh & (HH - 1);
    #pragma unroll
    for (int p = 0; p < 4; ++p) {
        int g = tid + p * 512;
        int r = g >> 3;
        int c = (g & 7) << 3;
        *(uint4*)&Op[((size_t)(b*SS + q0 + r))*DD + h*DHH + c] = *(uint4*)&PS(r, c);
    }
#undef PS
}

// ---------------------------------------------------------------------------

extern "C" void kernel_launch(void* const* d_in, const int* in_sizes, int n_in,
                              void* d_out, int out_size, void* d_ws, size_t ws_size,
                              hipStream_t stream)
{
    const float* x     = (const float*)d_in[0];
    const float* W_qkv = (const float*)d_in[1];
    const float* b_qkv = (const float*)d_in[2];
    const float* W_out = (const float*)d_in[3];
    const float* b_out = (const float*)d_in[4];
    float* out = (float*)d_out;

    __bf16* ws  = (__bf16*)d_ws;
    __bf16* xb  = ws;                          // 8388608
    __bf16* wqb = xb  + (size_t)8388608;       // 3145728
    __bf16* wob = wqb + (size_t)3145728;       // 1048576
    __bf16* qp  = wob + (size_t)1048576;       // 8388608 each
    __bf16* kp  = qp  + (size_t)8388608;
    __bf16* vp  = kp  + (size_t)8388608;
    __bf16* op  = vp  + (size_t)8388608;

    cvt_all<<<12288, 256, 0, stream>>>(
        (const float4*)x, (const float4*)W_qkv, (const float4*)W_out,
        (ushort4*)xb, (ushort4*)wqb, (ushort4*)wob);

    qkv_gemm<<<dim3(MM/128, 3*DD/128), 256, 0, stream>>>(xb, wqb, b_qkv, qp, kp, vp);
    attn_mfma<<<dim3(SS/256, BB*HH), 512, 0, stream>>>(qp, kp, vp, op);
    out_gemm<<<dim3(MM/128, DD/128), 256, 0, stream>>>(op, wob, b_out, out);
}

// Round 5
// 253.627 us; speedup vs baseline: 1.0426x; 1.0426x over previous
//
#include <hip/hip_runtime.h>

#define BB 4
#define SS 2048
#define DD 1024
#define HH 16
#define DHH 64
#define MM (BB*SS)          // 8192

typedef __bf16 bf16x8 __attribute__((ext_vector_type(8)));
typedef __bf16 bf16x4 __attribute__((ext_vector_type(4)));
typedef float  f32x4  __attribute__((ext_vector_type(4)));
typedef float  f32x16 __attribute__((ext_vector_type(16)));
typedef unsigned int u32;
typedef unsigned int u32x4 __attribute__((ext_vector_type(4)));

__device__ __forceinline__ unsigned short f2bf(float x) {
    unsigned int u = __float_as_uint(x);
    u += 0x7FFFu + ((u >> 16) & 1u);          // RNE
    return (unsigned short)(u >> 16);
}

// Async global->LDS, 16B/lane. LDS dst is wave-uniform base + lane*16.
__device__ __forceinline__ void glds16(const __bf16* g, __bf16* l) {
    __builtin_amdgcn_global_load_lds(
        (const __attribute__((address_space(1))) void*)g,
        (__attribute__((address_space(3))) void*)l, 16, 0, 0);
}

// ---------------------------------------------------------------------------
// fp32 -> bf16, all three inputs in one launch.
// ---------------------------------------------------------------------------
__global__ __launch_bounds__(256) void cvt_all(
    const float4* __restrict__ x,  const float4* __restrict__ wq,
    const float4* __restrict__ wo,
    ushort4* __restrict__ xb, ushort4* __restrict__ wqb, ushort4* __restrict__ wob)
{
    int i = blockIdx.x * 256 + threadIdx.x;
    const float4* src; ushort4* dst; int j;
    if (i < 2097152)      { src = x;  dst = xb;  j = i; }
    else if (i < 2883584) { src = wq; dst = wqb; j = i - 2097152; }
    else                  { src = wo; dst = wob; j = i - 2883584; }
    float4 v = src[j];
    ushort4 o;
    o.x = f2bf(v.x); o.y = f2bf(v.y); o.z = f2bf(v.z); o.w = f2bf(v.w);
    dst[j] = o;
}

// ---------------------------------------------------------------------------
// MFMA GEMM (B^T): C[m,n] = sum_k A[m,k] * W[n,k]. 128x128 tile, BK=64,
// 4 waves (2x2 of 64x64), 16x16x32 frags. Staging via global_load_lds
// width=16 into unpadded [128][64] tiles, rotate-by-row granule swizzle
// (2-way bank aliasing per 16-lane phase = free).
// ---------------------------------------------------------------------------
__global__ __launch_bounds__(256) void qkv_gemm(
    const __bf16* __restrict__ A,             // [8192,1024] x
    const __bf16* __restrict__ W,             // [3072,1024] W_qkv
    const float* __restrict__ bias,           // [3072]
    __bf16* __restrict__ Qp,                  // [64][2048][64], pre-scaled
    __bf16* __restrict__ Kp,                  // [64][2048][64]
    __bf16* __restrict__ Vp)                  // [64][64][2048] transposed
{
    __shared__ __bf16 smem[16896];            // As(8192) | Bs(8192); CT[128][132]
#define CT(r,c) smem[(r)*132 + (c)]
    __bf16* As = smem;
    __bf16* Bs = smem + 8192;
    const int tid  = threadIdx.x;
    const int m0   = blockIdx.x * 128;
    const int n0   = blockIdx.y * 128;
    const int lane = tid & 63;
    const int wid  = tid >> 6;
    const int fr   = lane & 15;
    const int quad = lane >> 4;
    const int wm   = (wid >> 1) * 64;
    const int wn   = (wid & 1) * 64;

    const int srow = lane >> 3;               // 0..7 within a wave-chunk
    const int sg   = ((lane & 7) - srow) & 7; // swizzled granule to fetch

    f32x4 acc[4][4] = {};

    for (int k0 = 0; k0 < DD; k0 += 64) {
        __syncthreads();
        #pragma unroll
        for (int p = 0; p < 4; ++p) {
            int cidx = p * 4 + wid;           // 0..15 -> rows 8*cidx..+7
            int r = cidx * 8 + srow;
            glds16(A + (size_t)(m0 + r) * DD + k0 + sg * 8, As + cidx * 512);
            glds16(W + (size_t)(n0 + r) * DD + k0 + sg * 8, Bs + cidx * 512);
        }
        __syncthreads();

        bf16x8 af[2][4], bw[2][4];
        #pragma unroll
        for (int kc = 0; kc < 2; ++kc)
            #pragma unroll
            for (int t = 0; t < 4; ++t) {
                int col = ((kc * 4 + quad + fr) & 7) * 8;
                af[kc][t] = *(const bf16x8*)&As[(wm + t*16 + fr) * 64 + col];
                bw[kc][t] = *(const bf16x8*)&Bs[(wn + t*16 + fr) * 64 + col];
            }
        #pragma unroll
        for (int kc = 0; kc < 2; ++kc)
            #pragma unroll
            for (int mt = 0; mt < 4; ++mt)
                #pragma unroll
                for (int nt = 0; nt < 4; ++nt)
                    acc[mt][nt] = __builtin_amdgcn_mfma_f32_16x16x32_bf16(
                        af[kc][mt], bw[kc][nt], acc[mt][nt], 0, 0, 0);
    }

    __syncthreads();                          // staging reads done; reuse smem
    const int t3 = n0 >> 10;                  // 0=q, 1=k, 2=v (uniform/block)
    const int b  = m0 >> 11;
    const int s0 = m0 & (SS - 1);

    float bn[4];
    #pragma unroll
    for (int nt = 0; nt < 4; ++nt) bn[nt] = bias[n0 + wn + nt*16 + fr];

    if (t3 == 2) {
        // V: store tile TRANSPOSED in LDS: CT[n-local][m-local], packed b64.
        #pragma unroll
        for (int nt = 0; nt < 4; ++nt)
            #pragma unroll
            for (int mt = 0; mt < 4; ++mt) {
                f32x4 t;
                #pragma unroll
                for (int i = 0; i < 4; ++i) t[i] = acc[mt][nt][i] + bn[nt];
                *(bf16x4*)&CT(wn + nt*16 + fr, wm + mt*16 + quad*4) =
                    __builtin_convertvector(t, bf16x4);
            }
        __syncthreads();
        const int pn0 = n0 - 2048;
        #pragma unroll
        for (int p = 0; p < 8; ++p) {
            int g = tid + p * 256;
            int r = g >> 4;                   // n-local 0..127
            int c = (g & 15) << 3;            // m-local 0..120
            int pn = pn0 + r, h = pn >> 6, dh = pn & 63;
            *(uint4*)&Vp[((size_t)((b*HH + h)*DHH + dh))*SS + s0 + c] = *(uint4*)&CT(r, c);
        }
    } else {
        __bf16* dst = (t3 == 0) ? Qp : Kp;
        // Q pre-scale folds 1/sqrt(64) AND log2(e) (softmax uses exp2).
        const float qscale = (t3 == 0) ? 0.125f * 1.44269504088896340736f : 1.0f;
        #pragma unroll
        for (int nt = 0; nt < 4; ++nt)
            #pragma unroll
            for (int mt = 0; mt < 4; ++mt)
                #pragma unroll
                for (int i = 0; i < 4; ++i)
                    CT(wm + mt*16 + quad*4 + i, wn + nt*16 + fr) =
                        (__bf16)((acc[mt][nt][i] + bn[nt]) * qscale);
        __syncthreads();
        const int pn0 = (t3 == 0) ? n0 : n0 - 1024;
        #pragma unroll
        for (int p = 0; p < 8; ++p) {
            int g = tid + p * 256;
            int r = g >> 4;                   // m-local (s) 0..127
            int c = (g & 15) << 3;            // n-local 0..120
            int pn = pn0 + c, h = pn >> 6, dh = pn & 63;
            *(uint4*)&dst[((size_t)((b*HH + h))*SS + s0 + r)*DHH + dh] = *(uint4*)&CT(r, c);
        }
    }
#undef CT
}

__global__ __launch_bounds__(256) void out_gemm(
    const __bf16* __restrict__ A,             // [8192,1024] O bf16
    const __bf16* __restrict__ W,             // [1024,1024] W_out bf16
    const float* __restrict__ bias,           // [1024]
    float* __restrict__ out)                  // [8192,1024] fp32
{
    __shared__ __bf16 smem[16384];            // As(8192) | Bs(8192)
    __bf16* As = smem;
    __bf16* Bs = smem + 8192;
    const int tid  = threadIdx.x;
    const int m0   = blockIdx.x * 128;
    const int n0   = blockIdx.y * 128;
    const int lane = tid & 63;
    const int wid  = tid >> 6;
    const int fr   = lane & 15;
    const int quad = lane >> 4;
    const int wm   = (wid >> 1) * 64;
    const int wn   = (wid & 1) * 64;

    const int srow = lane >> 3;
    const int sg   = ((lane & 7) - srow) & 7;

    f32x4 acc[4][4] = {};

    for (int k0 = 0; k0 < DD; k0 += 64) {
        __syncthreads();
        #pragma unroll
        for (int p = 0; p < 4; ++p) {
            int cidx = p * 4 + wid;
            int r = cidx * 8 + srow;
            glds16(A + (size_t)(m0 + r) * DD + k0 + sg * 8, As + cidx * 512);
            glds16(W + (size_t)(n0 + r) * DD + k0 + sg * 8, Bs + cidx * 512);
        }
        __syncthreads();

        bf16x8 af[2][4], bw[2][4];
        #pragma unroll
        for (int kc = 0; kc < 2; ++kc)
            #pragma unroll
            for (int t = 0; t < 4; ++t) {
                int col = ((kc * 4 + quad + fr) & 7) * 8;
                af[kc][t] = *(const bf16x8*)&As[(wm + t*16 + fr) * 64 + col];
                bw[kc][t] = *(const bf16x8*)&Bs[(wn + t*16 + fr) * 64 + col];
            }
        #pragma unroll
        for (int kc = 0; kc < 2; ++kc)
            #pragma unroll
            for (int mt = 0; mt < 4; ++mt)
                #pragma unroll
                for (int nt = 0; nt < 4; ++nt)
                    acc[mt][nt] = __builtin_amdgcn_mfma_f32_16x16x32_bf16(
                        af[kc][mt], bw[kc][nt], acc[mt][nt], 0, 0, 0);
    }

    #pragma unroll
    for (int nt = 0; nt < 4; ++nt) {
        int n  = n0 + wn + nt*16 + fr;
        float bnv = bias[n];
        #pragma unroll
        for (int mt = 0; mt < 4; ++mt) {
            #pragma unroll
            for (int i = 0; i < 4; ++i) {
                int m = m0 + wm + mt*16 + quad*4 + i;
                out[(size_t)m * DD + n] = acc[mt][nt][i] + bnv;
            }
        }
    }
}

// ---------------------------------------------------------------------------
// MFMA flash attention v11 = v10 + XCD-aware block mapping (T1).
// R3 post-mortem: bench total was flat across attn 93->77 while profiled
// FETCH_SIZE = 139 MB vs ~48 MB ideal -> the 8 q-blocks sharing one bh's
// K/V land on 8 different XCDs (linear wgid round-robin), so every XCD
// re-fetches K+V. Remap (bijective, 512 = 8 XCD x 64): XCD x owns bh
// 8x..8x+7 (all 8 q-blocks of each, 64 blocks, all co-resident at 2/CU x
// 32 CU). Per-XCD K+V working set = 8 x 512KB = 4MB = one XCD L2.
// ---------------------------------------------------------------------------
__global__ __launch_bounds__(512, 4) void attn_mfma(
    const __bf16* __restrict__ Qp,            // [bh][s][dh], pre-scaled
    const __bf16* __restrict__ Kp,            // [bh][s][dh]
    const __bf16* __restrict__ Vp,            // [bh][dh][s]  (transposed)
    __bf16* __restrict__ Op)                  // [8192][1024] (b,s,h*dh)
{
    // [0,16384)      Ks[2][4096]  (rot-8 swizzled, double-buffered)
    // [16384,32768)  VT[2][4096]  (rot-8 swizzled, double-buffered)
    // [0,36864)      Ps[256][72]  (EPILOGUE ONLY - aliases staging)
    // [36864,37888)  Ls[256]      (denominators, non-aliased)
    __shared__ __align__(16) char smem[37888];
    __bf16* const KsB = (__bf16*)smem;
    __bf16* const VTB = (__bf16*)(smem + 16384);
    float*  const Ls  = (float*)(smem + 36864);
#define PS(r,c) (((__bf16*)smem)[(r)*72 + (c)])

    const int tid  = threadIdx.x;
    // XCD-aware decode: xcd = wg&7; XCD x gets bh 8x..8x+7, q-blocks grouped.
    const int wg   = blockIdx.x;
    const int xcd  = wg & 7;
    const int slot = wg >> 3;                 // 0..63
    const int bh   = xcd * 8 + (slot >> 3);   // 8 bh per XCD
    const int q0   = (slot & 7) * 256;
    const size_t base = (size_t)bh * SS * DHH;
    const int lane = tid & 63;
    const int wid  = tid >> 6;                // 0..7
    const int c32  = lane & 31;               // row/col index in 32-wide frags
    const int hi   = lane >> 5;               // half-wave select
    const int wrow = wid * 32;                // this wave's q-rows in tile

    const int srow = lane >> 3;
    const int sg   = ((lane & 7) - srow) & 7;

    // 8 waves each stage 8 rows of K and 8 rows of V (1 glds16 each).
#define STAGE_KV(buf, kt_)                                                        \
    {                                                                             \
        int r = wid * 8 + srow;                                                   \
        glds16(Kp + base + (size_t)((kt_) + r) * DHH + sg * 8,                    \
               KsB + (buf) * 4096 + wid * 512);                                   \
        glds16(Vp + base + (size_t)r * SS + (kt_) + sg * 8,                       \
               VTB + (buf) * 4096 + wid * 512);                                   \
    }

    // Q B-frags from global: B[k=d][col=q]; lane holds Q[q=c32][ks*16+hi*8+j].
    bf16x8 bq[4];
    #pragma unroll
    for (int ks = 0; ks < 4; ++ks)
        bq[ks] = *(const bf16x8*)
            (Qp + base + (size_t)(q0 + wrow + c32) * DHH + ks*16 + hi*8);

    f32x16 o[2] = {};                         // o[dt]
    float lp = 0.0f;

    STAGE_KV(0, 0)
    __syncthreads();                          // prologue tile landed

    int cur = 0;
    for (int kt = 0; kt < SS; kt += 64) {
        if (kt + 64 < SS) STAGE_KV(cur ^ 1, kt + 64)   // async prefetch
        const __bf16* Kc = KsB + cur * 4096;
        const __bf16* Vc = VTB + cur * 4096;

        u32 pw[2][8];                         // packed P A-frags [kt2][dword]

        // S^T = K Q^T, 32x32x16: D[key = (reg&3)+8*(reg>>2)+4*hi][q = c32].
        #pragma unroll
        for (int kt2 = 0; kt2 < 2; ++kt2) {
            bf16x8 bk[4];
            #pragma unroll
            for (int ks = 0; ks < 4; ++ks)
                bk[ks] = *(const bf16x8*)
                    &Kc[(kt2*32 + c32) * 64 + ((ks*2 + hi + c32) & 7) * 8];
            f32x16 s = {};
            __builtin_amdgcn_s_setprio(1);
            #pragma unroll
            for (int ks = 0; ks < 4; ++ks)
                s = __builtin_amdgcn_mfma_f32_32x32x16_bf16(
                    bk[ks], bq[ks], s, 0, 0, 0);
            __builtin_amdgcn_s_setprio(0);
            #pragma unroll
            for (int e = 0; e < 16; ++e) s[e] = __builtin_amdgcn_exp2f(s[e]);
            lp += ((s[0]+s[1])+(s[2]+s[3])) + ((s[4]+s[5])+(s[6]+s[7]))
                + ((s[8]+s[9])+(s[10]+s[11])) + ((s[12]+s[13])+(s[14]+s[15]));
            // T12 relayout: 4 cvt_pk + 2 permlane32_swap per 16-key step.
            #pragma unroll
            for (int kk = 0; kk < 2; ++kk) {
                u32 wa, wb, wc, wd;
                asm("v_cvt_pk_bf16_f32 %0, %1, %2" : "=v"(wa) : "v"(s[kk*8+0]), "v"(s[kk*8+1]));
                asm("v_cvt_pk_bf16_f32 %0, %1, %2" : "=v"(wb) : "v"(s[kk*8+4]), "v"(s[kk*8+5]));
                asm("v_cvt_pk_bf16_f32 %0, %1, %2" : "=v"(wc) : "v"(s[kk*8+2]), "v"(s[kk*8+3]));
                asm("v_cvt_pk_bf16_f32 %0, %1, %2" : "=v"(wd) : "v"(s[kk*8+6]), "v"(s[kk*8+7]));
                asm("v_permlane32_swap_b32 %0, %1" : "+v"(wa), "+v"(wb));
                asm("v_permlane32_swap_b32 %0, %1" : "+v"(wc), "+v"(wd));
                pw[kt2][kk*4+0] = wa;
                pw[kt2][kk*4+1] = wc;
                pw[kt2][kk*4+2] = wb;
                pw[kt2][kk*4+3] = wd;
            }
        }

        // O += P V, 32x32x16: A = P[q][k] (in-register), B = V[k][d] from VT.
        #pragma unroll
        for (int ks = 0; ks < 4; ++ks) {
            const int kt2 = ks >> 1, kk = ks & 1;
            bf16x8 bv[2];
            #pragma unroll
            for (int dt = 0; dt < 2; ++dt)
                bv[dt] = *(const bf16x8*)
                    &Vc[(dt*32 + c32) * 64 + ((ks*2 + hi + c32) & 7) * 8];
            u32x4 t = { pw[kt2][kk*4+0], pw[kt2][kk*4+1],
                        pw[kt2][kk*4+2], pw[kt2][kk*4+3] };
            bf16x8 pa = __builtin_bit_cast(bf16x8, t);
            __builtin_amdgcn_s_setprio(1);
            #pragma unroll
            for (int dt = 0; dt < 2; ++dt)
                o[dt] = __builtin_amdgcn_mfma_f32_32x32x16_bf16(
                    pa, bv[dt], o[dt], 0, 0, 0);
            __builtin_amdgcn_s_setprio(0);
        }

        __syncthreads();                      // drains prefetch + syncs bufs
        cur ^= 1;
    }
#undef STAGE_KV

    // Denominators: lane (q=c32, hi) holds 32 of 64 keys/round; partner
    // half-wave has the rest -> single xor-32 reduce. Same-wave LDS use.
    {
        float v = lp + __shfl_xor(lp, 32);
        Ls[wrow + c32] = v;                   // both hi write same value
    }

    // Normalize O (D[row=q][col=d], row = (reg&3)+8*(reg>>2)+4*hi) and stage
    // into Ps (which aliases the now-dead staging buffers).
    #pragma unroll
    for (int r = 0; r < 16; ++r) {
        int row = wrow + (r & 3) + 8*(r >> 2) + 4*hi;
        float inv = 1.0f / Ls[row];
        #pragma unroll
        for (int dt = 0; dt < 2; ++dt)
            PS(row, dt*32 + c32) = (__bf16)(o[dt][r] * inv);
    }
    __syncthreads();

    const int b = bh >> 4, h = bh & (HH - 1);
    #pragma unroll
    for (int p = 0; p < 4; ++p) {
        int g = tid + p * 512;
        int r = g >> 3;
        int c = (g & 7) << 3;
        *(uint4*)&Op[((size_t)(b*SS + q0 + r))*DD + h*DHH + c] = *(uint4*)&PS(r, c);
    }
#undef PS
}

// ---------------------------------------------------------------------------

extern "C" void kernel_launch(void* const* d_in, const int* in_sizes, int n_in,
                              void* d_out, int out_size, void* d_ws, size_t ws_size,
                              hipStream_t stream)
{
    const float* x     = (const float*)d_in[0];
    const float* W_qkv = (const float*)d_in[1];
    const float* b_qkv = (const float*)d_in[2];
    const float* W_out = (const float*)d_in[3];
    const float* b_out = (const float*)d_in[4];
    float* out = (float*)d_out;

    __bf16* ws  = (__bf16*)d_ws;
    __bf16* xb  = ws;                          // 8388608
    __bf16* wqb = xb  + (size_t)8388608;       // 3145728
    __bf16* wob = wqb + (size_t)3145728;       // 1048576
    __bf16* qp  = wob + (size_t)1048576;       // 8388608 each
    __bf16* kp  = qp  + (size_t)8388608;
    __bf16* vp  = kp  + (size_t)8388608;
    __bf16* op  = vp  + (size_t)8388608;

    cvt_all<<<12288, 256, 0, stream>>>(
        (const float4*)x, (const float4*)W_qkv, (const float4*)W_out,
        (ushort4*)xb, (ushort4*)wqb, (ushort4*)wob);

    qkv_gemm<<<dim3(MM/128, 3*DD/128), 256, 0, stream>>>(xb, wqb, b_qkv, qp, kp, vp);
    attn_mfma<<<dim3(512, 1), 512, 0, stream>>>(qp, kp, vp, op);
    out_gemm<<<dim3(MM/128, DD/128), 256, 0, stream>>>(op, wob, b_out, out);
}